// Round 6
// baseline (456.246 us; speedup 1.0000x reference)
//
#include <hip/hip_runtime.h>
#include <stdint.h>

namespace {

constexpr int kBH = 128;
constexpr int kS  = 1024;
constexpr int kD  = 64;
constexpr int kQB = 32;
constexpr int kT  = 8;                           // tiles per persistent WG
constexpr float kScale = 0.04419417382415922f;   // 1/sqrt(512)
constexpr float kNegInf = -3.0e38f;

typedef __attribute__((ext_vector_type(8))) short short8;   // 8 bf16
typedef __attribute__((ext_vector_type(4))) short short4v;  // 4 bf16 (8 B)
typedef __attribute__((ext_vector_type(4))) float f32x4;
typedef __attribute__((ext_vector_type(4))) int   i32x4;
typedef __attribute__((ext_vector_type(2))) unsigned int u32x2;

__device__ inline uint16_t f2bf(float f) {       // f32 -> bf16 bits, RNE
    union { float f; uint32_t u; } x; x.f = f;
    uint32_t r = x.u + 0x7fffu + ((x.u >> 16) & 1u);
    return (uint16_t)(r >> 16);
}
__device__ inline float bf2f(uint16_t h) {
    union { uint32_t u; float f; } x; x.u = ((uint32_t)h) << 16;
    return x.f;
}
__device__ inline uint32_t pkbf(float lo, float hi) {
    return (uint32_t)f2bf(lo) | ((uint32_t)f2bf(hi) << 16);
}
__device__ inline float unlo(uint32_t w) { return bf2f((uint16_t)(w & 0xffffu)); }
__device__ inline float unhi(uint32_t w) { return bf2f((uint16_t)(w >> 16)); }

// ---- prep 1: K f32 [bh][k][d] -> bf16 same layout ----
__global__ __launch_bounds__(256)
void conv_k_kernel(const float* __restrict__ K, uint16_t* __restrict__ Kb) {
    const size_t base = ((size_t)blockIdx.x * 256 + threadIdx.x) * 8;
    f32x4 a = *(const f32x4*)(K + base);
    f32x4 b = *(const f32x4*)(K + base + 4);
    short8 t;
    #pragma unroll
    for (int j = 0; j < 4; ++j) { t[j] = (short)f2bf(a[j]); t[j + 4] = (short)f2bf(b[j]); }
    *(short8*)(Kb + base) = t;
}

// ---- prep 2: V f32 [bh][k][d] -> bf16 transposed Vt [bh][d][k] ----
__global__ __launch_bounds__(256)
void transp_v_kernel(const float* __restrict__ V, uint16_t* __restrict__ Vt) {
    __shared__ float t[64][65];
    const int bh = blockIdx.x >> 4;
    const int kb = blockIdx.x & 15;
    const int tid = threadIdx.x;
    const float* vb = V + ((size_t)bh * kS + kb * 64) * kD;
    #pragma unroll
    for (int rep = 0; rep < 4; ++rep) {
        const int k = (tid >> 4) + rep * 16;
        const int d4 = (tid & 15) * 4;
        f32x4 x = *(const f32x4*)(vb + (size_t)k * kD + d4);
        #pragma unroll
        for (int j = 0; j < 4; ++j) t[k][d4 + j] = x[j];
    }
    __syncthreads();
    const int d  = tid >> 2;
    const int kq = (tid & 3) * 16;
    short8 o0, o1;
    #pragma unroll
    for (int j = 0; j < 8; ++j) {
        o0[j] = (short)f2bf(t[kq + j][d]);
        o1[j] = (short)f2bf(t[kq + 8 + j][d]);
    }
    uint16_t* orow = Vt + ((size_t)bh * kD + d) * kS + kb * 64 + kq;
    *(short8*)(orow)     = o0;
    *(short8*)(orow + 8) = o1;
}

__global__ __launch_bounds__(512, 4)             // VGPR<=128, 2 WG/CU (LDS-capped)
void sdpa_kernel(const float* __restrict__ Q, const uint16_t* __restrict__ Kb,
                 const uint16_t* __restrict__ Vt, const int* __restrict__ M,
                 float* __restrict__ Og, float* __restrict__ Ag) {
    __shared__ uint16_t P_lds[kQB * kS];         // 64 KiB scores->p (bf16, XOR-swz)
    __shared__ uint16_t mb[2][kQB][64];          // 8 KiB mask bits, double-buffered
    __shared__ float inv_lds[kQB];               // total ~72.1 KiB -> 2 WG/CU

    // persistent mapping: WG g -> XCD (g&7); 8 WGs share a bh (tile slots);
    // 4 consecutive tiles per bh, then switch to bh+8 on the same XCD.
    const int g    = blockIdx.x;
    const int xcd  = g & 7;
    const int jj   = g >> 3;                     // 0..63 within XCD
    const int pid  = jj >> 3;                    // 0..7
    const int slot = jj & 7;                     // 0..7
    const int bh0  = xcd * 16 + pid;

    const int tid  = threadIdx.x;
    const int wave = tid >> 6;
    const int lane = tid & 63;
    const int l16  = lane & 15;
    const int lg   = lane >> 4;

    auto t_bh = [&](int t) { return (t < 4) ? bh0 : (bh0 + 8); };
    auto t_q0 = [&](int t) { return (slot * 4 + (t & 3)) * kQB; };

    // mask prefetch: wave owns rows 4*wave..4*wave+3; chunk h covers 2 rows.
    // per row: 4 x i32x4/lane, wave-contiguous 1 KiB per load -> perfectly coalesced.
    auto mask_issue = [&](int bh, int q0, int h, i32x4 ld[2][4]) {
        const int* mbase = M + ((size_t)bh * kS + q0 + 4 * wave + 2 * h) * kS + lane * 4;
        #pragma unroll
        for (int p = 0; p < 2; ++p)
            #pragma unroll
            for (int c = 0; c < 4; ++c)
                ld[p][c] = __builtin_nontemporal_load((const i32x4*)(mbase + (size_t)p * kS + c * 256));
    };
    // pack to bits: lane's u16 = nibbles for cols {c*256+4*lane .. +3}, c=0..3
    auto mask_pack = [&](int h, int buf, i32x4 ld[2][4]) {
        #pragma unroll
        for (int p = 0; p < 2; ++p) {
            uint32_t v = 0;
            #pragma unroll
            for (int c = 0; c < 4; ++c) {
                i32x4 m = ld[p][c];
                uint32_t nib = (m.x ? 1u : 0u) | (m.y ? 2u : 0u) | (m.z ? 4u : 0u) | (m.w ? 8u : 0u);
                v |= nib << (4 * c);
            }
            mb[buf][4 * wave + 2 * h + p][lane] = (uint16_t)v;
        }
    };

    // ---- prologue: mask bits for tile 0 -> mb[0] ----
    {
        i32x4 lda[2][4], ldb[2][4];
        mask_issue(t_bh(0), t_q0(0), 0, lda);
        mask_issue(t_bh(0), t_q0(0), 1, ldb);
        mask_pack(0, 0, lda);
        mask_pack(1, 0, ldb);
    }
    __syncthreads();

    for (int t = 0; t < kT; ++t) {
        const int cur = t & 1, nxt = cur ^ 1;
        const int bh = t_bh(t), q0 = t_q0(t);
        const int tn  = (t + 1 < kT) ? t + 1 : t;
        const int bhn = t_bh(tn), q0n = t_q0(tn);
        const uint16_t* kbb = Kb + (size_t)bh * kS * kD;

        // ---- Q frags for this tile: B-operand B[k=lg*8+j][col=l16 -> q-row] ----
        short8 afr[2][2];
        #pragma unroll
        for (int m = 0; m < 2; ++m)
        #pragma unroll
        for (int ks = 0; ks < 2; ++ks) {
            const float* p = Q + ((size_t)bh * kS + q0 + m * 16 + l16) * kD + ks * 32 + lg * 8;
            f32x4 lo = *(const f32x4*)p;
            f32x4 hi = *(const f32x4*)(p + 4);
            short8 tt;
            #pragma unroll
            for (int j = 0; j < 4; ++j) { tt[j] = (short)f2bf(lo[j]); tt[j + 4] = (short)f2bf(hi[j]); }
            afr[m][ks] = tt;
        }

        // ---- PH1: S^T = K·Q^T -> P_lds (lane holds 4 consecutive cols of a q-row) ----
        const int n0 = wave * 128;
        #pragma unroll 2
        for (int nt = 0; nt < 8; ++nt) {
            const int nb = n0 + nt * 16;
            const uint16_t* krow = kbb + (size_t)(nb + l16) * kD + lg * 8;
            short8 kf0 = *(const short8*)(krow);
            short8 kf1 = *(const short8*)(krow + 32);
            #pragma unroll
            for (int m = 0; m < 2; ++m) {
                f32x4 acc = {0.f, 0.f, 0.f, 0.f};
                acc = __builtin_amdgcn_mfma_f32_16x16x32_bf16(kf0, afr[m][0], acc, 0, 0, 0);
                acc = __builtin_amdgcn_mfma_f32_16x16x32_bf16(kf1, afr[m][1], acc, 0, 0, 0);
                const int rowq = m * 16 + l16;
                const int e = rowq * kS + ((nb + lg * 4) ^ ((rowq & 7) << 3));
                u32x2 w; w.x = pkbf(acc[0], acc[1]); w.y = pkbf(acc[2], acc[3]);
                *(u32x2*)(P_lds + e) = w;
            }
        }

        i32x4 lda[2][4];                          // mask(t+1) chunk A in flight over PH2
        if (t + 1 < kT) mask_issue(bhn, q0n, 0, lda);
        __syncthreads();                          // B1: P scores readable

        // ---- PH2: mask(LDS bits)+scale -> max -> exp -> sum -> attn store + p->LDS ----
        #pragma unroll
        for (int round = 0; round < 2; ++round) {
            const int row = round * 16 + (tid >> 5);  // 16 rows x 32 threads
            const int c0  = (tid & 31) * 4;
            const int swz = (row & 7) << 3;
            uint16_t* prow = P_lds + row * kS;
            const uint32_t mw0 = mb[cur][row][tid & 31];
            const uint32_t mw1 = mb[cur][row][(tid & 31) + 32];

            u32x2 ps[8];
            float mx = kNegInf;
            #pragma unroll
            for (int i = 0; i < 8; ++i) {
                short4v s4 = *(const short4v*)(prow + ((c0 + i * 128) ^ swz));
                const uint32_t nib = (((i & 1) ? mw1 : mw0) >> (4 * (i >> 1))) & 0xFu;
                float v0 = (nib & 1u) ? kNegInf : bf2f((uint16_t)s4.x) * kScale;
                float v1 = (nib & 2u) ? kNegInf : bf2f((uint16_t)s4.y) * kScale;
                float v2 = (nib & 4u) ? kNegInf : bf2f((uint16_t)s4.z) * kScale;
                float v3 = (nib & 8u) ? kNegInf : bf2f((uint16_t)s4.w) * kScale;
                ps[i].x = pkbf(v0, v1); ps[i].y = pkbf(v2, v3);
                mx = fmaxf(mx, fmaxf(fmaxf(v0, v1), fmaxf(v2, v3)));
            }
            #pragma unroll
            for (int o = 16; o; o >>= 1) mx = fmaxf(mx, __shfl_xor(mx, o));

            float sum = 0.f;
            #pragma unroll
            for (int i = 0; i < 8; ++i) {
                float p0 = __expf(unlo(ps[i].x) - mx);
                float p1 = __expf(unhi(ps[i].x) - mx);
                float p2 = __expf(unlo(ps[i].y) - mx);
                float p3 = __expf(unhi(ps[i].y) - mx);
                sum += (p0 + p1) + (p2 + p3);
                u32x2 w; w.x = pkbf(p0, p1); w.y = pkbf(p2, p3);
                ps[i] = w;
                *(u32x2*)(prow + ((c0 + i * 128) ^ swz)) = w;   // unnormalized p
            }
            #pragma unroll
            for (int o = 16; o; o >>= 1) sum += __shfl_xor(sum, o);
            const float inv = 1.0f / sum;
            if ((tid & 31) == 0) inv_lds[row] = inv;

            float* arow = Ag + ((size_t)bh * kS + q0 + row) * kS;
            #pragma unroll
            for (int i = 0; i < 8; ++i) {
                f32x4 a = { unlo(ps[i].x) * inv, unhi(ps[i].x) * inv,
                            unlo(ps[i].y) * inv, unhi(ps[i].y) * inv };
                *(f32x4*)(arow + c0 + i * 128) = a;             // coalesced f32x4
            }
        }

        i32x4 ldb[2][4];                          // mask(t+1) chunk B in flight over PH3
        if (t + 1 < kT) {
            mask_pack(0, nxt, lda);
            mask_issue(bhn, q0n, 1, ldb);
        }
        __syncthreads();                          // B2: p + mb[nxt].A visible

        // ---- PH3: O = P @ V; wave -> one 16x16 tile, full K; Vt from L2 ----
        {
            const int m  = wave >> 2;
            const int d0 = (wave & 3) * 16;
            const uint16_t* vtrow = Vt + ((size_t)bh * kD + d0 + l16) * kS + lg * 8;
            const uint16_t* pbase = P_lds + (size_t)(m * 16 + l16) * kS;
            const int aswz = (l16 & 7) << 3;
            f32x4 acc0 = {0.f, 0.f, 0.f, 0.f};
            f32x4 acc1 = {0.f, 0.f, 0.f, 0.f};
            #pragma unroll
            for (int kk = 0; kk < 32; kk += 2) {
                short8 a0 = *(const short8*)(pbase + ((kk * 32 + lg * 8) ^ aswz));
                short8 b0 = *(const short8*)(vtrow + kk * 32);
                acc0 = __builtin_amdgcn_mfma_f32_16x16x32_bf16(a0, b0, acc0, 0, 0, 0);
                short8 a1 = *(const short8*)(pbase + (((kk + 1) * 32 + lg * 8) ^ aswz));
                short8 b1 = *(const short8*)(vtrow + (kk + 1) * 32);
                acc1 = __builtin_amdgcn_mfma_f32_16x16x32_bf16(a1, b1, acc1, 0, 0, 0);
            }
            f32x4 acc = acc0 + acc1;
            f32x4 invv = *(const f32x4*)(inv_lds + m * 16 + lg * 4);
            float* orow = Og + ((size_t)bh * kS + q0 + m * 16 + lg * 4) * kD + d0 + l16;
            #pragma unroll
            for (int r = 0; r < 4; ++r) orow[(size_t)r * kD] = acc[r] * invv[r];
        }

        if (t + 1 < kT) mask_pack(1, nxt, ldb);
        __syncthreads();                          // B3: P_lds free, mb[nxt] complete
    }
}

} // namespace

extern "C" void kernel_launch(void* const* d_in, const int* in_sizes, int n_in,
                              void* d_out, int out_size, void* d_ws, size_t ws_size,
                              hipStream_t stream) {
    const float* q = (const float*)d_in[0];
    const float* k = (const float*)d_in[1];
    const float* v = (const float*)d_in[2];
    const int*   m = (const int*)d_in[3];
    float* og = (float*)d_out;
    float* ag = og + (size_t)kBH * kS * kD;      // outputs concatenated: O then attn

    uint16_t* kb = (uint16_t*)d_ws;              // 16.78 MB bf16 K
    uint16_t* vt = kb + (size_t)kBH * kS * kD;   // 16.78 MB bf16 V^T [bh][d][k]

    conv_k_kernel<<<dim3(4096), dim3(256), 0, stream>>>(k, kb);
    transp_v_kernel<<<dim3(2048), dim3(256), 0, stream>>>(v, vt);
    sdpa_kernel<<<dim3(512), dim3(512), 0, stream>>>(q, kb, vt, m, og, ag);
}